// Round 13
// baseline (409.681 us; speedup 1.0000x reference)
//
#include <hip/hip_runtime.h>
#include <hip/hip_bf16.h>

// AttentiveGraph: B=4, N=10000, E=160000, C=F=128, 3 iterations.
// R23: R22's 4-pass fill regressed (fill leg = 256 blocks x 4x work -> long
// pole, K4 48->61us). Revert to R21 and restructure the fill leg instead:
// GLOBAL-ATOMIC cursor fill. scanC writes cur_g[b][n] = row_start; fill leg
// does p=atomicAdd(&cur_g[e.x],1); edb[p]=e.y directly from conn.
//   - K4 LDS drops 40960 -> 16896 (init leg's) => ~9 blocks/CU;
//   - fill leg scales to 640 blocks (1000 edges each), no 1-block/CU pole;
//   - row-internal edge order becomes atomic-nondeterministic (already true
//     within chunks; sums are permutation-equivalent within tolerance).
// K1 keeps packed u16 hist (20KB LDS). Edge kernel (R20 verified), mids,
// final, colscan unchanged from R21 (339us best).

#define BATCH 4
#define NNODE 10000
#define NEDGE 160000
#define TWOE  (2*NEDGE)
#define MROWS (BATCH*NNODE)   // 40000
#define NCHUNK 64
#define CHUNKE (NEDGE/NCHUNK) // 2500
#define PADN  10240
#define EDPAD (TWOE + 8*NNODE) // 400000: padded edge capacity per batch

typedef unsigned short u16;
typedef unsigned int   u32;
typedef __attribute__((ext_vector_type(8))) short bf16x8_t;
typedef __attribute__((ext_vector_type(4))) float f32x4_t;

__device__ __forceinline__ float b2f(u16 h){ return __uint_as_float(((u32)h) << 16); }
__device__ __forceinline__ u16 f2bf(float f){
  u32 u = __float_as_uint(f);
  return (u16)((u + 0x7fffu + ((u >> 16) & 1u)) >> 16);   // RNE
}
__device__ __forceinline__ float fast_tanh(float x){
  float e = __expf(2.0f * x);
  return fmaf(-2.0f, __builtin_amdgcn_rcpf(e + 1.0f), 1.0f);
}

__device__ __forceinline__ void chunk_of(int blk, int& b, int& c){
  int xcd = blk & 7;
  b = xcd >> 1;
  c = ((blk >> 3) << 1) | (xcd & 1);           // 0..63
}

// ---------------- K1: csr_hist [0,256) || prep_weights [256,513) --------------
// hist packed: word n>>1, halfword n&1; per-chunk counts <= 10000 < 65536.
__global__ void __launch_bounds__(256) k1_prep_hist(const int* __restrict__ conn,
    u16* __restrict__ partial,
    const void* __restrict__ objects,
    const void* __restrict__ Wo, const void* __restrict__ Wa,
    const void* __restrict__ Wla, const void* __restrict__ Wl,
    const void* __restrict__ ab, const void* __restrict__ sb,
    int* __restrict__ flag, u16* __restrict__ Wt, float* __restrict__ biasf){
  __shared__ u32 hist[NNODE / 2];              // 20000B
  __shared__ int zc, hc;
  if (blockIdx.x < 256){
    // ---- csr_hist (packed counters) ----
    int b, c; chunk_of(blockIdx.x, b, c);
    for (int n = threadIdx.x; n < NNODE / 2; n += 256) hist[n] = 0;
    __syncthreads();
    const int2* cp = (const int2*)conn + (size_t)b * NEDGE + c * CHUNKE;
    for (int i = threadIdx.x; i < CHUNKE; i += 256){
      int2 e = cp[i];
      atomicAdd(&hist[e.x >> 1], 1u << ((e.x & 1) << 4));
      atomicAdd(&hist[e.y >> 1], 1u << ((e.y & 1) << 4));
    }
    __syncthreads();
    u16* prow = partial + (size_t)(b * NCHUNK + c) * PADN;
    for (int n = threadIdx.x; n < NNODE; n += 256)
      prow[n] = (u16)(hist[n >> 1] >> ((n & 1) << 4));
  } else {
    // ---- prep_weights (with fused dtype probe) ----
    if (threadIdx.x == 0){ zc = 0; hc = 0; }
    __syncthreads();
    const u32* objw = (const u32*)objects;
    int z = 0, hcnt = 0;
    for (int i = threadIdx.x; i < 1024; i += 256){
      u32 lo = objw[i] & 0xffffu;
      if (lo == 0) z++;
      if (((lo >> 7) & 0xffu) >= 160u) hcnt++;
    }
    atomicAdd(&zc, z); atomicAdd(&hc, hcnt);
    __syncthreads();
    bool f = (hc > 0 || zc > 512);              // 1 = fp32 storage
    int p = blockIdx.x - 256;
    if (p == 0 && threadIdx.x == 0) *flag = f ? 1 : 0;
    int idx = p * 256 + threadIdx.x;
    if (idx < 65536){
      int m = idx >> 14, k = (idx >> 7) & 127, c = idx & 127;
      const void* src = (m == 0) ? Wo : (m == 1) ? Wa : (m == 2) ? Wla : Wl;
      u16 h = f ? f2bf(((const float*)src)[k * 128 + c]) : ((const u16*)src)[k * 128 + c];
      Wt[m * 16384 + c * 128 + k] = h;
    } else {
      int t = idx - 65536;
      const void* src = (t < 128) ? sb : ab;
      int i = t & 127;
      biasf[t] = f ? ((const float*)src)[i] : b2f(((const u16*)src)[i]);
    }
  }
}

// ---------------- CSR scans -----------------------------------------------------
__global__ void __launch_bounds__(256) csr_colscan(u16* __restrict__ partial,
    int* __restrict__ row_start, int* __restrict__ bsum, int* __restrict__ deg){
  int b = blockIdx.x / 40, w = blockIdx.x % 40;
  int n = w * 256 + threadIdx.x;
  u32 run = 0;
  if (n < NNODE){
    #pragma unroll 8
    for (int c = 0; c < NCHUNK; c++){
      size_t idx = (size_t)(b * NCHUNK + c) * PADN + n;
      run += partial[idx];
    }
  }
  u32 pad = (run + 7u) & ~7u;
  __shared__ u32 buf[256];
  buf[threadIdx.x] = pad;
  __syncthreads();
  for (int off = 1; off < 256; off <<= 1){
    u32 x = (threadIdx.x >= (unsigned)off) ? buf[threadIdx.x - off] : 0;
    __syncthreads();
    buf[threadIdx.x] += x;
    __syncthreads();
  }
  u32 incl = buf[threadIdx.x];
  if (n < NNODE){
    row_start[b * (NNODE + 1) + n] = (int)(incl - pad);  // window-local padded
    deg[b * NNODE + n] = (int)run;
  }
  if (threadIdx.x == 255) bsum[blockIdx.x] = (int)incl;
}

// scanC: finalize row_start and seed the global fill cursors.
__global__ void scanC(int* __restrict__ row_start, const int* __restrict__ bsum,
                      int* __restrict__ cur_g){
  int b = blockIdx.x / 40, j = blockIdx.x % 40;
  int n = j * 256 + threadIdx.x;
  int off = 0;
  for (int q = b * 40; q < b * 40 + j; q++) off += bsum[q];
  if (n < NNODE){
    int v = row_start[b * (NNODE + 1) + n] + off;
    row_start[b * (NNODE + 1) + n] = v;
    cur_g[b * NNODE + n] = v;
  }
  if (j == 39 && threadIdx.x == 0)
    row_start[b * (NNODE + 1) + NNODE] = off + bsum[b * 40 + 39];
}

// ---------------- MFMA helpers (wave = 16 rows x 64 cols) ---------------------
__device__ __forceinline__ void gemm_tile4(const u16* __restrict__ arow,
    const u16* __restrict__ wt, int lm, int lq, int cofs, f32x4_t acc[4]){
  #pragma unroll
  for (int ks = 0; ks < 4; ks++){
    bf16x8_t a = *(const bf16x8_t*)(arow + ks * 32);
    #pragma unroll
    for (int nb = 0; nb < 4; nb++){
      bf16x8_t bfr = *(const bf16x8_t*)(wt + (cofs + nb * 16 + lm) * 128 + ks * 32 + lq * 8);
      acc[nb] = __builtin_amdgcn_mfma_f32_16x16x32_bf16(a, bfr, acc[nb], 0, 0, 0);
    }
  }
}

__device__ __forceinline__ void gemm_tile4_packed(const u32* __restrict__ Lrow,
    const u16* __restrict__ wt, int lm, int lq, int cofs, f32x4_t acc[4]){
  #pragma unroll
  for (int ks = 0; ks < 4; ks++){
    uint4 wa = *(const uint4*)(Lrow + ks * 32 + lq * 8);
    uint4 wb = *(const uint4*)(Lrow + ks * 32 + lq * 8 + 4);
    bf16x8_t a;
    a[0] = (short)wa.x; a[1] = (short)wa.y; a[2] = (short)wa.z; a[3] = (short)wa.w;
    a[4] = (short)wb.x; a[5] = (short)wb.y; a[6] = (short)wb.z; a[7] = (short)wb.w;
    #pragma unroll
    for (int nb = 0; nb < 4; nb++){
      bf16x8_t bfr = *(const bf16x8_t*)(wt + (cofs + nb * 16 + lm) * 128 + ks * 32 + lq * 8);
      acc[nb] = __builtin_amdgcn_mfma_f32_16x16x32_bf16(a, bfr, acc[nb], 0, 0, 0);
    }
  }
}

// phase 2: states tile (LDS, pointer-based) -> gat {S fp16 hi | EL fp16 lo}
// u32 stores + ea fp16 into eat tile.
__device__ __forceinline__ void phase2_awlaw4(const u16* __restrict__ ldstile,
    const u16* __restrict__ Wt, const float* __restrict__ biasf,
    int lm, int lq, int cofs, int r0, _Float16* __restrict__ eat,
    u32* __restrict__ ghw){
  const u16* Wta  = Wt + 16384;
  const u16* Wtla = Wt + 32768;
  const u16* ldsrow = ldstile + lm * 136 + lq * 8;
  f32x4_t accA[4], accL[4];
  #pragma unroll
  for (int i = 0; i < 4; i++){ accA[i] = (f32x4_t){0.f,0.f,0.f,0.f}; accL[i] = (f32x4_t){0.f,0.f,0.f,0.f}; }
  #pragma unroll
  for (int ks = 0; ks < 4; ks++){
    bf16x8_t a = *(const bf16x8_t*)(ldsrow + ks * 32);
    #pragma unroll
    for (int nb = 0; nb < 4; nb++){
      bf16x8_t ba = *(const bf16x8_t*)(Wta  + (cofs + nb * 16 + lm) * 128 + ks * 32 + lq * 8);
      bf16x8_t bl = *(const bf16x8_t*)(Wtla + (cofs + nb * 16 + lm) * 128 + ks * 32 + lq * 8);
      accA[nb] = __builtin_amdgcn_mfma_f32_16x16x32_bf16(a, ba, accA[nb], 0, 0, 0);
      accL[nb] = __builtin_amdgcn_mfma_f32_16x16x32_bf16(a, bl, accL[nb], 0, 0, 0);
    }
  }
  #pragma unroll
  for (int nb = 0; nb < 4; nb++){
    int col = cofs + nb * 16 + lm;
    float bb = biasf[128 + col];
    #pragma unroll
    for (int i = 0; i < 4; i++){
      int row = r0 + lq * 4 + i;
      float ea = fminf(__expf(accA[nb][i]), 60000.0f);   // fp16-safe
      eat[(lq * 4 + i) * 128 + col] = (_Float16)ea;
      _Float16 elh = (_Float16)fminf(__expf(accL[nb][i] + bb), 60000.0f);
      u16 sbf = ldstile[(lq * 4 + i) * 136 + col];
      _Float16 sh = (_Float16)b2f(sbf);                  // bf16 -> fp16 exact
      u32 elu = (u32)(*(const u16*)&elh);
      u32 shu = (u32)(*(const u16*)&sh);
      ghw[(size_t)row * 64 + (col & 63)] = elu | (shu << 16);
    }
  }
}

// coalesced eah writeback: 2 tiles x 16 rows x 128 fp16 = 8KB, 16B/thread x2.
__device__ __forceinline__ void eah_writeback(const _Float16* __restrict__ eat,
    _Float16* __restrict__ eah, int blk_r0, int tid){
  const uint4* src = (const uint4*)eat;       // 512 x 16B
  uint4* dst = (uint4*)(eah + (size_t)blk_r0 * 128);
  dst[tid]       = src[tid];
  dst[tid + 256] = src[tid + 256];
}

// init body (pointer-based shared), shared by K4.
__device__ __forceinline__ void fused_init_body(int blk, int tid,
    const void* __restrict__ obj_raw, const int* __restrict__ flag,
    const u16* __restrict__ Wt, const float* __restrict__ biasf,
    _Float16* __restrict__ eah, u32* __restrict__ gat0, u32* __restrict__ gat1,
    u16* __restrict__ lds, _Float16* __restrict__ eat){
  const int lane = tid & 63, wave = tid >> 6;
  const int t = wave >> 1, ch = wave & 1, cofs = ch * 64;
  const int r0 = blk * 32 + t * 16;
  const int lm = lane & 15, lq = lane >> 4;
  u16* ldsT = lds + t * 2176;                  // 16*136
  _Float16* eatT = eat + t * 2048;             // 16*128
  f32x4_t acc[4];
  #pragma unroll
  for (int i = 0; i < 4; i++) acc[i] = (f32x4_t){0.f, 0.f, 0.f, 0.f};
  if (*flag){
    const float* arow = (const float*)obj_raw + (size_t)(r0 + lm) * 128 + lq * 8;
    #pragma unroll
    for (int ks = 0; ks < 4; ks++){
      float4 fa = *(const float4*)(arow + ks * 32);
      float4 fb = *(const float4*)(arow + ks * 32 + 4);
      bf16x8_t a;
      a[0] = (short)f2bf(fa.x); a[1] = (short)f2bf(fa.y);
      a[2] = (short)f2bf(fa.z); a[3] = (short)f2bf(fa.w);
      a[4] = (short)f2bf(fb.x); a[5] = (short)f2bf(fb.y);
      a[6] = (short)f2bf(fb.z); a[7] = (short)f2bf(fb.w);
      #pragma unroll
      for (int nb = 0; nb < 4; nb++){
        bf16x8_t bfr = *(const bf16x8_t*)(Wt + (cofs + nb * 16 + lm) * 128 + ks * 32 + lq * 8);
        acc[nb] = __builtin_amdgcn_mfma_f32_16x16x32_bf16(a, bfr, acc[nb], 0, 0, 0);
      }
    }
  } else {
    gemm_tile4((const u16*)obj_raw + (size_t)(r0 + lm) * 128 + lq * 8, Wt, lm, lq, cofs, acc);
  }
  #pragma unroll
  for (int nb = 0; nb < 4; nb++){
    int col = cofs + nb * 16 + lm;
    float bb = biasf[col];
    #pragma unroll
    for (int i = 0; i < 4; i++)
      ldsT[(lq * 4 + i) * 136 + col] = f2bf(fast_tanh(acc[nb][i] + bb));
  }
  __syncthreads();
  phase2_awlaw4(ldsT, Wt, biasf, lm, lq, cofs, r0, eatT, ch ? gat1 : gat0);
  __syncthreads();
  eah_writeback(eat, eah, blk * 32, tid);
}

// ---------------- K4: fused_init || global-atomic fill || pad_fill ------------
// blocks: [0,1250) init, [1250,1890) fill (640 blocks x 1000 edges),
//         [1890,2050) pad.
__global__ void __launch_bounds__(256) k4_init_fill_pad(
    const void* __restrict__ obj_raw, const int* __restrict__ flag,
    const u16* __restrict__ Wt, const float* __restrict__ biasf,
    _Float16* __restrict__ eah, u32* __restrict__ gat0, u32* __restrict__ gat1,
    const int* __restrict__ conn, const int* __restrict__ row_start,
    int* __restrict__ edge_dst, const int* __restrict__ deg,
    int* __restrict__ cur_g){
  __shared__ __align__(16) char smem[16896];
  int blk = blockIdx.x;
  if (blk < 1250){
    // ---- fused_init ----
    u16* lds = (u16*)smem;                       // 8704B
    _Float16* eat = (_Float16*)(smem + 8704);    // 8192B
    fused_init_body(blk, (int)threadIdx.x, obj_raw, flag, Wt, biasf,
                    eah, gat0, gat1, lds, eat);
  } else if (blk < 1890){
    // ---- fill: global-atomic cursors, 1000 edges/block ----
    int p = blk - 1250;
    int b = p / 160, seg = p % 160;
    const int2* cp = (const int2*)conn + (size_t)b * NEDGE + seg * 1000;
    int* edb = edge_dst + (size_t)b * EDPAD;
    int* cg = cur_g + b * NNODE;
    for (int i = threadIdx.x; i < 1000; i += 256){
      int2 e = cp[i];
      int p1 = atomicAdd(&cg[e.x], 1); edb[p1] = e.y;
      int p2 = atomicAdd(&cg[e.y], 1); edb[p2] = e.x;
    }
  } else {
    // ---- pad_fill (+ sentinel gat rows + batch tail fill) ----
    int p = blk - 1890;
    if (p == 0){
      size_t base = (size_t)MROWS * 64;
      gat0[base + threadIdx.x] = 0;
      gat1[base + threadIdx.x] = 0;
    }
    int b = p / 40, j = p % 40;
    const int* rs = row_start + b * (NNODE + 1);
    int sent = 40000 - 9999 * b;   // local d -> global gat row 40000+b (zero)
    int* edb = edge_dst + (size_t)b * EDPAD;
    if (j == 0){                    // fill uninitialized batch tail
      int T = rs[NNODE];
      for (int q = T + (int)threadIdx.x; q < EDPAD; q += 256) edb[q] = sent;
    }
    int n = j * 256 + threadIdx.x;
    if (n < NNODE){
      int s = rs[n] + deg[b * NNODE + n];
      int epad = rs[n + 1];
      for (int q = s; q < epad; q++) edb[q] = sent;
    }
  }
}

// mid: states = tanh(sa + lg@Wl + b); then eah/EL/S for next iter.
__global__ void __launch_bounds__(256) fused_mid(const u32* __restrict__ lgsa,
    const u16* __restrict__ Wt, const float* __restrict__ biasf,
    _Float16* __restrict__ eah, u32* __restrict__ gat0, u32* __restrict__ gat1){
  __shared__ u16 lds[2][16 * 136];
  __shared__ _Float16 eat[2][16 * 128];
  const int lane = threadIdx.x & 63, wave = threadIdx.x >> 6;
  const int t = wave >> 1, ch = wave & 1, cofs = ch * 64;
  const int r0 = blockIdx.x * 32 + t * 16;
  const int lm = lane & 15, lq = lane >> 4;
  f32x4_t acc[4];
  #pragma unroll
  for (int i = 0; i < 4; i++) acc[i] = (f32x4_t){0.f, 0.f, 0.f, 0.f};
  gemm_tile4_packed(lgsa + (size_t)(r0 + lm) * 128, Wt + 49152, lm, lq, cofs, acc);
  #pragma unroll
  for (int nb = 0; nb < 4; nb++){
    int col = cofs + nb * 16 + lm;
    float bb = biasf[col];
    #pragma unroll
    for (int i = 0; i < 4; i++){
      int row = r0 + lq * 4 + i;
      u32 v = lgsa[(size_t)row * 128 + col];
      u16 hb = (u16)(v >> 16);
      float sa = (float)(*(const _Float16*)&hb);
      lds[t][(lq * 4 + i) * 136 + col] = f2bf(fast_tanh(sa + acc[nb][i] + bb));
    }
  }
  __syncthreads();
  phase2_awlaw4(&lds[t][0], Wt, biasf, lm, lq, cofs, r0, &eat[t][0], ch ? gat1 : gat0);
  __syncthreads();
  eah_writeback(&eat[0][0], eah, blockIdx.x * 32, threadIdx.x);
}

// final: out = tanh(sa + lg@Wl + b), fp32 or bf16 per flag.
__global__ void __launch_bounds__(256) final_out(const u32* __restrict__ lgsa,
    const u16* __restrict__ Wt, const float* __restrict__ biasf,
    const int* __restrict__ flag, void* __restrict__ outp){
  const int lane = threadIdx.x & 63, wave = threadIdx.x >> 6;
  const int t = wave >> 1, ch = wave & 1, cofs = ch * 64;
  const int r0 = blockIdx.x * 32 + t * 16;
  const int lm = lane & 15, lq = lane >> 4;
  bool f32out = (*flag != 0);
  f32x4_t acc[4];
  #pragma unroll
  for (int i = 0; i < 4; i++) acc[i] = (f32x4_t){0.f, 0.f, 0.f, 0.f};
  gemm_tile4_packed(lgsa + (size_t)(r0 + lm) * 128, Wt + 49152, lm, lq, cofs, acc);
  #pragma unroll
  for (int nb = 0; nb < 4; nb++){
    int col = cofs + nb * 16 + lm;
    float bb = biasf[col];
    #pragma unroll
    for (int i = 0; i < 4; i++){
      int row = r0 + lq * 4 + i;
      u32 vv = lgsa[(size_t)row * 128 + col];
      u16 hb = (u16)(vv >> 16);
      float sa = (float)(*(const _Float16*)&hb);
      float v = fast_tanh(sa + acc[nb][i] + bb);
      if (f32out) ((float*)outp)[(size_t)row * 128 + col] = v;
      else        ((u16*)  outp)[(size_t)row * 128 + col] = f2bf(v);
    }
  }
}

// ---------------- edge gather: 2 node-chains per wave (R20, verified) ---------
__device__ __forceinline__ void acc_mix(u32 g, float one, float& a1, float& a2){
  asm("v_fma_mix_f32 %0, %2, %3, %0 op_sel:[0,0,0] op_sel_hi:[1,0,0]\n\t"
      "v_fma_mix_f32 %1, %2, %2, %1 op_sel:[0,1,0] op_sel_hi:[1,1,0]"
      : "+v"(a1), "+v"(a2)
      : "v"(g), "v"(one));
}

__device__ __forceinline__ u32 gath1(const u32* __restrict__ gh, int d, int c){
  const u32* p = (const u32*)((const char*)gh + ((size_t)(u32)d << 8));
  return p[c];
}

#define LDIDX(d, p) { const int* ep_ = (p); _Pragma("unroll") \
  for (int j = 0; j < 8; j++) d[j] = __builtin_amdgcn_readfirstlane(ep_[j]); }
#define GATH8(g, d) { _Pragma("unroll") \
  for (int j = 0; j < 8; j++) g[j] = gath1(gh, d[j], c); }
#define CONS8(g, s1, s2, t1, t2) { _Pragma("unroll") \
  for (int j = 0; j < 8; j++) acc_mix(g[j], one, (j & 1) ? t1 : s1, (j & 1) ? t2 : s2); }

__global__ void __launch_bounds__(128, 6) edge_kernel(const _Float16* __restrict__ eah,
    const u32* __restrict__ gat0, const u32* __restrict__ gat1,
    const int* __restrict__ row_start, const int* __restrict__ edge_dst,
    u32* __restrict__ lgsa){
  int blk = blockIdx.x;
  int xcd = blk & 7;
  int b = xcd >> 1, h = xcd & 1;
  int i = blk >> 3;                          // 0..2499
  int w = (int)(threadIdx.x >> 6);
  int nA = i * 4 + w * 2, nB = nA + 1;
  int c = threadIdx.x & 63;
  const u32* gh = (h ? gat1 : gat0) + (size_t)b * NNODE * 64;
  const int* rs = row_start + b * (NNODE + 1);
  int eA  = __builtin_amdgcn_readfirstlane(rs[nA]);
  int eA1 = __builtin_amdgcn_readfirstlane(rs[nA + 1]);
  int eB1 = __builtin_amdgcn_readfirstlane(rs[nB + 1]);
  int eB = eA1;
  const int* ed = edge_dst + (size_t)b * EDPAD;

  float eaA = (float)eah[(size_t)(b * NNODE + nA) * 128 + h * 64 + c];
  float eaB = (float)eah[(size_t)(b * NNODE + nB) * 128 + h * 64 + c];
  u32 selfA = gh[((size_t)nA << 6) + c];
  u32 selfB = gh[((size_t)nB << 6) + c];
  const float one = 1.0f;

  float sA1=0.f, sA2=0.f, tA1=0.f, tA2=0.f;
  float sB1=0.f, sB2=0.f, tB1=0.f, tB2=0.f;
  int ngA = (eA1 - eA) >> 3, ngB = (eB1 - eB) >> 3;  // rows padded: len%8==0
  int dA[8], dB[8]; u32 gA[8], gB[8], hA[8], hB[8];

  if (ngA){ LDIDX(dA, ed + eA); }
  if (ngB){ LDIDX(dB, ed + eB); }
  if (ngA){ GATH8(gA, dA); eA += 8; LDIDX(dA, ed + eA); }
  if (ngB){ GATH8(gB, dB); eB += 8; LDIDX(dB, ed + eB); }

  int m = ngA < ngB ? ngA : ngB;
  int cons = 0;
  for (; cons + 2 <= m; cons += 2){
    GATH8(hA, dA); eA += 8; LDIDX(dA, ed + eA);
    GATH8(hB, dB); eB += 8; LDIDX(dB, ed + eB);
    CONS8(gA, sA1, sA2, tA1, tA2);
    CONS8(gB, sB1, sB2, tB1, tB2);
    GATH8(gA, dA); eA += 8; LDIDX(dA, ed + eA);
    GATH8(gB, dB); eB += 8; LDIDX(dB, ed + eB);
    CONS8(hA, sA1, sA2, tA1, tA2);
    CONS8(hB, sB1, sB2, tB1, tB2);
  }

  { int rem = ngA - cons;
    if (rem > 0){
      int k = 1;
      for (; k + 1 < rem; k += 2){
        GATH8(hA, dA); eA += 8; LDIDX(dA, ed + eA);
        CONS8(gA, sA1, sA2, tA1, tA2);
        GATH8(gA, dA); eA += 8; LDIDX(dA, ed + eA);
        CONS8(hA, sA1, sA2, tA1, tA2);
      }
      if (k < rem){
        GATH8(hA, dA);
        CONS8(gA, sA1, sA2, tA1, tA2);
        CONS8(hA, sA1, sA2, tA1, tA2);
      } else {
        CONS8(gA, sA1, sA2, tA1, tA2);
      }
    }
  }
  { int rem = ngB - cons;
    if (rem > 0){
      int k = 1;
      for (; k + 1 < rem; k += 2){
        GATH8(hB, dB); eB += 8; LDIDX(dB, ed + eB);
        CONS8(gB, sB1, sB2, tB1, tB2);
        GATH8(gB, dB); eB += 8; LDIDX(dB, ed + eB);
        CONS8(hB, sB1, sB2, tB1, tB2);
      }
      if (k < rem){
        GATH8(hB, dB);
        CONS8(gB, sB1, sB2, tB1, tB2);
        CONS8(hB, sB1, sB2, tB1, tB2);
      } else {
        CONS8(gB, sB1, sB2, tB1, tB2);
      }
    }
  }

  sA1 += tA1; sA2 += tA2; sB1 += tB1; sB2 += tB2;
  { float inv = __builtin_amdgcn_rcpf(fmaf(eaA, sA1, 1.0f));
    float lg = eaA * sA2 * inv;
    u16 hb = (u16)(selfA >> 16);
    float s_self = (float)(*(const _Float16*)&hb);
    _Float16 hs = (_Float16)(s_self * inv);
    u32 pk = (u32)f2bf(lg) | ((u32)(*(const u16*)&hs) << 16);
    lgsa[(size_t)(b * NNODE + nA) * 128 + h * 64 + c] = pk; }
  { float inv = __builtin_amdgcn_rcpf(fmaf(eaB, sB1, 1.0f));
    float lg = eaB * sB2 * inv;
    u16 hb = (u16)(selfB >> 16);
    float s_self = (float)(*(const _Float16*)&hb);
    _Float16 hs = (_Float16)(s_self * inv);
    u32 pk = (u32)f2bf(lg) | ((u32)(*(const u16*)&hs) << 16);
    lgsa[(size_t)(b * NNODE + nB) * 128 + h * 64 + c] = pk; }
}

// ---------------- host launcher ----------------------------------------------
extern "C" void kernel_launch(void* const* d_in, const int* in_sizes, int n_in,
                              void* d_out, int out_size, void* d_ws, size_t ws_size,
                              hipStream_t stream){
  (void)in_sizes; (void)n_in; (void)ws_size; (void)out_size;
  const void* objects = d_in[0];
  const void* Wo      = d_in[1];
  const void* Wa      = d_in[2];
  const void* Wla     = d_in[3];
  const void* attn_b  = d_in[4];
  const void* Wl      = d_in[5];
  const void* state_b = d_in[6];
  const int*  conn    = (const int*)d_in[7];

  char* base = (char*)d_ws;
  size_t off = 0;
  auto alloc = [&](size_t bytes) -> char* {
    char* p = base + off;
    off = (off + bytes + 255) & ~(size_t)255;
    return p;
  };
  int*      flag      = (int*)     alloc(256);
  u16*      Wt        = (u16*)     alloc((size_t)4 * 16384 * 2);
  float*    biasf     = (float*)   alloc(256 * 4);
  _Float16* eah       = (_Float16*)alloc((size_t)MROWS * 128 * 2);       // exp(aW) fp16
  u32*      gat0      = (u32*)     alloc((size_t)(MROWS + 4) * 64 * 4);  // ch 0-63 {S|EL} + 4 zero rows
  u32*      gat1      = (u32*)     alloc((size_t)(MROWS + 4) * 64 * 4);  // ch 64-127 + 4 zero rows
  u32*      lgsa      = (u32*)     alloc((size_t)MROWS * 128 * 4);       // {lg bf16 | sa fp16}
  u16*      partial   = (u16*)     alloc((size_t)BATCH * NCHUNK * PADN * 2);
  int*      row_start = (int*)     alloc((size_t)BATCH * (NNODE + 1) * 4);
  int*      edge_dst  = (int*)     alloc((size_t)BATCH * EDPAD * 4);     // padded CSR
  int*      deg       = (int*)     alloc((size_t)MROWS * 4);
  int*      cur_g     = (int*)     alloc((size_t)MROWS * 4);             // fill cursors
  int*      bsum      = (int*)     alloc(160 * 4);

  k1_prep_hist<<<513, 256, 0, stream>>>(conn, partial, objects, Wo, Wa, Wla, Wl,
                                        attn_b, state_b, flag, Wt, biasf);
  csr_colscan<<<160, 256, 0, stream>>>(partial, row_start, bsum, deg);
  scanC<<<160, 256, 0, stream>>>(row_start, bsum, cur_g);
  k4_init_fill_pad<<<2050, 256, 0, stream>>>(objects, flag, Wt, biasf, eah,
                                             gat0, gat1, conn, row_start,
                                             edge_dst, deg, cur_g);

  edge_kernel<<<MROWS / 2, 128, 0, stream>>>(eah, gat0, gat1, row_start, edge_dst, lgsa);
  fused_mid<<<MROWS / 32, 256, 0, stream>>>(lgsa, Wt, biasf, eah, gat0, gat1);
  edge_kernel<<<MROWS / 2, 128, 0, stream>>>(eah, gat0, gat1, row_start, edge_dst, lgsa);
  fused_mid<<<MROWS / 32, 256, 0, stream>>>(lgsa, Wt, biasf, eah, gat0, gat1);
  edge_kernel<<<MROWS / 2, 128, 0, stream>>>(eah, gat0, gat1, row_start, edge_dst, lgsa);
  final_out<<<MROWS / 32, 256, 0, stream>>>(lgsa, Wt, biasf, flag, d_out);
}

// Round 14
// 343.291 us; speedup vs baseline: 1.1934x; 1.1934x over previous
//
#include <hip/hip_runtime.h>
#include <hip/hip_bf16.h>

// AttentiveGraph: B=4, N=10000, E=160000, C=F=128, 3 iterations.
// R24: R23's global-atomic fill catastrophically serialized (K4 48->146us,
// WRITE 44->111MB: L2 thrash from read-returning atomics + random 4B writes).
// Revert to R21's K4 structure (LDS-cursor single-pass fill, 339us total) and
// fix its occupancy limiter instead: PACK the fill cursors 2xu16 per u32
// (offsets bounded by degree << 65536; packed atomicAdd returns old word,
// extract halfword; position = rs[n] + offset with rs L1/L2-cached). partial's
// u16 rows ARE the packed initial image -> cursor init is a u32 copy.
// K4 LDS high-water 40960 -> 20000 => 8 blocks/CU (2x R21) for all legs.
// K1 keeps R22's packed hist (proven). Everything else = R21 exactly:
// edge R20 2-chain gather, mids, final, colscan/scanC, fused dispatches.

#define BATCH 4
#define NNODE 10000
#define NEDGE 160000
#define TWOE  (2*NEDGE)
#define MROWS (BATCH*NNODE)   // 40000
#define NCHUNK 64
#define CHUNKE (NEDGE/NCHUNK) // 2500
#define PADN  10240
#define EDPAD (TWOE + 8*NNODE) // 400000: padded edge capacity per batch

typedef unsigned short u16;
typedef unsigned int   u32;
typedef __attribute__((ext_vector_type(8))) short bf16x8_t;
typedef __attribute__((ext_vector_type(4))) float f32x4_t;

__device__ __forceinline__ float b2f(u16 h){ return __uint_as_float(((u32)h) << 16); }
__device__ __forceinline__ u16 f2bf(float f){
  u32 u = __float_as_uint(f);
  return (u16)((u + 0x7fffu + ((u >> 16) & 1u)) >> 16);   // RNE
}
__device__ __forceinline__ float fast_tanh(float x){
  float e = __expf(2.0f * x);
  return fmaf(-2.0f, __builtin_amdgcn_rcpf(e + 1.0f), 1.0f);
}

__device__ __forceinline__ void chunk_of(int blk, int& b, int& c){
  int xcd = blk & 7;
  b = xcd >> 1;
  c = ((blk >> 3) << 1) | (xcd & 1);           // 0..63
}

// ---------------- K1: csr_hist [0,256) || prep_weights [256,513) --------------
// hist packed: word n>>1, halfword n&1; per-chunk counts <= 10000 < 65536.
__global__ void __launch_bounds__(256) k1_prep_hist(const int* __restrict__ conn,
    u16* __restrict__ partial,
    const void* __restrict__ objects,
    const void* __restrict__ Wo, const void* __restrict__ Wa,
    const void* __restrict__ Wla, const void* __restrict__ Wl,
    const void* __restrict__ ab, const void* __restrict__ sb,
    int* __restrict__ flag, u16* __restrict__ Wt, float* __restrict__ biasf){
  __shared__ u32 hist[NNODE / 2];              // 20000B
  __shared__ int zc, hc;
  if (blockIdx.x < 256){
    // ---- csr_hist (packed counters) ----
    int b, c; chunk_of(blockIdx.x, b, c);
    for (int n = threadIdx.x; n < NNODE / 2; n += 256) hist[n] = 0;
    __syncthreads();
    const int2* cp = (const int2*)conn + (size_t)b * NEDGE + c * CHUNKE;
    for (int i = threadIdx.x; i < CHUNKE; i += 256){
      int2 e = cp[i];
      atomicAdd(&hist[e.x >> 1], 1u << ((e.x & 1) << 4));
      atomicAdd(&hist[e.y >> 1], 1u << ((e.y & 1) << 4));
    }
    __syncthreads();
    u16* prow = partial + (size_t)(b * NCHUNK + c) * PADN;
    for (int n = threadIdx.x; n < NNODE; n += 256)
      prow[n] = (u16)(hist[n >> 1] >> ((n & 1) << 4));
  } else {
    // ---- prep_weights (with fused dtype probe) ----
    if (threadIdx.x == 0){ zc = 0; hc = 0; }
    __syncthreads();
    const u32* objw = (const u32*)objects;
    int z = 0, hcnt = 0;
    for (int i = threadIdx.x; i < 1024; i += 256){
      u32 lo = objw[i] & 0xffffu;
      if (lo == 0) z++;
      if (((lo >> 7) & 0xffu) >= 160u) hcnt++;
    }
    atomicAdd(&zc, z); atomicAdd(&hc, hcnt);
    __syncthreads();
    bool f = (hc > 0 || zc > 512);              // 1 = fp32 storage
    int p = blockIdx.x - 256;
    if (p == 0 && threadIdx.x == 0) *flag = f ? 1 : 0;
    int idx = p * 256 + threadIdx.x;
    if (idx < 65536){
      int m = idx >> 14, k = (idx >> 7) & 127, c = idx & 127;
      const void* src = (m == 0) ? Wo : (m == 1) ? Wa : (m == 2) ? Wla : Wl;
      u16 h = f ? f2bf(((const float*)src)[k * 128 + c]) : ((const u16*)src)[k * 128 + c];
      Wt[m * 16384 + c * 128 + k] = h;
    } else {
      int t = idx - 65536;
      const void* src = (t < 128) ? sb : ab;
      int i = t & 127;
      biasf[t] = f ? ((const float*)src)[i] : b2f(((const u16*)src)[i]);
    }
  }
}

// ---------------- CSR scans (R21) ---------------------------------------------
__global__ void __launch_bounds__(256) csr_colscan(u16* __restrict__ partial,
    int* __restrict__ row_start, int* __restrict__ bsum, int* __restrict__ deg){
  int b = blockIdx.x / 40, w = blockIdx.x % 40;
  int n = w * 256 + threadIdx.x;
  u32 run = 0;
  if (n < NNODE){
    #pragma unroll 8
    for (int c = 0; c < NCHUNK; c++){
      size_t idx = (size_t)(b * NCHUNK + c) * PADN + n;
      u32 v = partial[idx];
      partial[idx] = (u16)run;                 // window-local prefix (cursor seed)
      run += v;
    }
  }
  u32 pad = (run + 7u) & ~7u;
  __shared__ u32 buf[256];
  buf[threadIdx.x] = pad;
  __syncthreads();
  for (int off = 1; off < 256; off <<= 1){
    u32 x = (threadIdx.x >= (unsigned)off) ? buf[threadIdx.x - off] : 0;
    __syncthreads();
    buf[threadIdx.x] += x;
    __syncthreads();
  }
  u32 incl = buf[threadIdx.x];
  if (n < NNODE){
    row_start[b * (NNODE + 1) + n] = (int)(incl - pad);  // window-local padded
    deg[b * NNODE + n] = (int)run;
  }
  if (threadIdx.x == 255) bsum[blockIdx.x] = (int)incl;
}

__global__ void scanC(int* __restrict__ row_start, const int* __restrict__ bsum){
  int b = blockIdx.x / 40, j = blockIdx.x % 40;
  int n = j * 256 + threadIdx.x;
  int off = 0;
  for (int q = b * 40; q < b * 40 + j; q++) off += bsum[q];
  if (n < NNODE) row_start[b * (NNODE + 1) + n] += off;
  if (j == 39 && threadIdx.x == 0)
    row_start[b * (NNODE + 1) + NNODE] = off + bsum[b * 40 + 39];
}

// ---------------- MFMA helpers (wave = 16 rows x 64 cols) ---------------------
__device__ __forceinline__ void gemm_tile4(const u16* __restrict__ arow,
    const u16* __restrict__ wt, int lm, int lq, int cofs, f32x4_t acc[4]){
  #pragma unroll
  for (int ks = 0; ks < 4; ks++){
    bf16x8_t a = *(const bf16x8_t*)(arow + ks * 32);
    #pragma unroll
    for (int nb = 0; nb < 4; nb++){
      bf16x8_t bfr = *(const bf16x8_t*)(wt + (cofs + nb * 16 + lm) * 128 + ks * 32 + lq * 8);
      acc[nb] = __builtin_amdgcn_mfma_f32_16x16x32_bf16(a, bfr, acc[nb], 0, 0, 0);
    }
  }
}

__device__ __forceinline__ void gemm_tile4_packed(const u32* __restrict__ Lrow,
    const u16* __restrict__ wt, int lm, int lq, int cofs, f32x4_t acc[4]){
  #pragma unroll
  for (int ks = 0; ks < 4; ks++){
    uint4 wa = *(const uint4*)(Lrow + ks * 32 + lq * 8);
    uint4 wb = *(const uint4*)(Lrow + ks * 32 + lq * 8 + 4);
    bf16x8_t a;
    a[0] = (short)wa.x; a[1] = (short)wa.y; a[2] = (short)wa.z; a[3] = (short)wa.w;
    a[4] = (short)wb.x; a[5] = (short)wb.y; a[6] = (short)wb.z; a[7] = (short)wb.w;
    #pragma unroll
    for (int nb = 0; nb < 4; nb++){
      bf16x8_t bfr = *(const bf16x8_t*)(wt + (cofs + nb * 16 + lm) * 128 + ks * 32 + lq * 8);
      acc[nb] = __builtin_amdgcn_mfma_f32_16x16x32_bf16(a, bfr, acc[nb], 0, 0, 0);
    }
  }
}

// phase 2: states tile (LDS, pointer-based) -> gat {S fp16 hi | EL fp16 lo}
// u32 stores + ea fp16 into eat tile.
__device__ __forceinline__ void phase2_awlaw4(const u16* __restrict__ ldstile,
    const u16* __restrict__ Wt, const float* __restrict__ biasf,
    int lm, int lq, int cofs, int r0, _Float16* __restrict__ eat,
    u32* __restrict__ ghw){
  const u16* Wta  = Wt + 16384;
  const u16* Wtla = Wt + 32768;
  const u16* ldsrow = ldstile + lm * 136 + lq * 8;
  f32x4_t accA[4], accL[4];
  #pragma unroll
  for (int i = 0; i < 4; i++){ accA[i] = (f32x4_t){0.f,0.f,0.f,0.f}; accL[i] = (f32x4_t){0.f,0.f,0.f,0.f}; }
  #pragma unroll
  for (int ks = 0; ks < 4; ks++){
    bf16x8_t a = *(const bf16x8_t*)(ldsrow + ks * 32);
    #pragma unroll
    for (int nb = 0; nb < 4; nb++){
      bf16x8_t ba = *(const bf16x8_t*)(Wta  + (cofs + nb * 16 + lm) * 128 + ks * 32 + lq * 8);
      bf16x8_t bl = *(const bf16x8_t*)(Wtla + (cofs + nb * 16 + lm) * 128 + ks * 32 + lq * 8);
      accA[nb] = __builtin_amdgcn_mfma_f32_16x16x32_bf16(a, ba, accA[nb], 0, 0, 0);
      accL[nb] = __builtin_amdgcn_mfma_f32_16x16x32_bf16(a, bl, accL[nb], 0, 0, 0);
    }
  }
  #pragma unroll
  for (int nb = 0; nb < 4; nb++){
    int col = cofs + nb * 16 + lm;
    float bb = biasf[128 + col];
    #pragma unroll
    for (int i = 0; i < 4; i++){
      int row = r0 + lq * 4 + i;
      float ea = fminf(__expf(accA[nb][i]), 60000.0f);   // fp16-safe
      eat[(lq * 4 + i) * 128 + col] = (_Float16)ea;
      _Float16 elh = (_Float16)fminf(__expf(accL[nb][i] + bb), 60000.0f);
      u16 sbf = ldstile[(lq * 4 + i) * 136 + col];
      _Float16 sh = (_Float16)b2f(sbf);                  // bf16 -> fp16 exact
      u32 elu = (u32)(*(const u16*)&elh);
      u32 shu = (u32)(*(const u16*)&sh);
      ghw[(size_t)row * 64 + (col & 63)] = elu | (shu << 16);
    }
  }
}

// coalesced eah writeback: 2 tiles x 16 rows x 128 fp16 = 8KB, 16B/thread x2.
__device__ __forceinline__ void eah_writeback(const _Float16* __restrict__ eat,
    _Float16* __restrict__ eah, int blk_r0, int tid){
  const uint4* src = (const uint4*)eat;       // 512 x 16B
  uint4* dst = (uint4*)(eah + (size_t)blk_r0 * 128);
  dst[tid]       = src[tid];
  dst[tid + 256] = src[tid + 256];
}

// init body (pointer-based shared), shared by K4.
__device__ __forceinline__ void fused_init_body(int blk, int tid,
    const void* __restrict__ obj_raw, const int* __restrict__ flag,
    const u16* __restrict__ Wt, const float* __restrict__ biasf,
    _Float16* __restrict__ eah, u32* __restrict__ gat0, u32* __restrict__ gat1,
    u16* __restrict__ lds, _Float16* __restrict__ eat){
  const int lane = tid & 63, wave = tid >> 6;
  const int t = wave >> 1, ch = wave & 1, cofs = ch * 64;
  const int r0 = blk * 32 + t * 16;
  const int lm = lane & 15, lq = lane >> 4;
  u16* ldsT = lds + t * 2176;                  // 16*136
  _Float16* eatT = eat + t * 2048;             // 16*128
  f32x4_t acc[4];
  #pragma unroll
  for (int i = 0; i < 4; i++) acc[i] = (f32x4_t){0.f, 0.f, 0.f, 0.f};
  if (*flag){
    const float* arow = (const float*)obj_raw + (size_t)(r0 + lm) * 128 + lq * 8;
    #pragma unroll
    for (int ks = 0; ks < 4; ks++){
      float4 fa = *(const float4*)(arow + ks * 32);
      float4 fb = *(const float4*)(arow + ks * 32 + 4);
      bf16x8_t a;
      a[0] = (short)f2bf(fa.x); a[1] = (short)f2bf(fa.y);
      a[2] = (short)f2bf(fa.z); a[3] = (short)f2bf(fa.w);
      a[4] = (short)f2bf(fb.x); a[5] = (short)f2bf(fb.y);
      a[6] = (short)f2bf(fb.z); a[7] = (short)f2bf(fb.w);
      #pragma unroll
      for (int nb = 0; nb < 4; nb++){
        bf16x8_t bfr = *(const bf16x8_t*)(Wt + (cofs + nb * 16 + lm) * 128 + ks * 32 + lq * 8);
        acc[nb] = __builtin_amdgcn_mfma_f32_16x16x32_bf16(a, bfr, acc[nb], 0, 0, 0);
      }
    }
  } else {
    gemm_tile4((const u16*)obj_raw + (size_t)(r0 + lm) * 128 + lq * 8, Wt, lm, lq, cofs, acc);
  }
  #pragma unroll
  for (int nb = 0; nb < 4; nb++){
    int col = cofs + nb * 16 + lm;
    float bb = biasf[col];
    #pragma unroll
    for (int i = 0; i < 4; i++)
      ldsT[(lq * 4 + i) * 136 + col] = f2bf(fast_tanh(acc[nb][i] + bb));
  }
  __syncthreads();
  phase2_awlaw4(ldsT, Wt, biasf, lm, lq, cofs, r0, eatT, ch ? gat1 : gat0);
  __syncthreads();
  eah_writeback(eat, eah, blk * 32, tid);
}

// ---------------- K4: fused_init || packed-cursor fill || pad_fill ------------
// blocks: [0,1250) init, [1250,1506) fill, [1506,1666) pad. LDS max = 20000B.
__global__ void __launch_bounds__(256) k4_init_fill_pad(
    const void* __restrict__ obj_raw, const int* __restrict__ flag,
    const u16* __restrict__ Wt, const float* __restrict__ biasf,
    _Float16* __restrict__ eah, u32* __restrict__ gat0, u32* __restrict__ gat1,
    const int* __restrict__ conn, const u16* __restrict__ partial,
    const int* __restrict__ row_start, int* __restrict__ edge_dst,
    const int* __restrict__ deg){
  __shared__ __align__(16) char smem[20000];
  int blk = blockIdx.x;
  if (blk < 1250){
    // ---- fused_init ----
    u16* lds = (u16*)smem;                       // 8704B
    _Float16* eat = (_Float16*)(smem + 8704);    // 8192B
    fused_init_body(blk, (int)threadIdx.x, obj_raw, flag, Wt, biasf,
                    eah, gat0, gat1, lds, eat);
  } else if (blk < 1506){
    // ---- csr_fill: packed 2xu16 LDS cursors; position = rs[n] + halfword ----
    int b, c; chunk_of(blk - 1250, b, c);
    u32* pk = (u32*)smem;                        // 20000B
    const u32* prow32 = (const u32*)(partial + (size_t)(b * NCHUNK + c) * PADN);
    const int* rs = row_start + b * (NNODE + 1);
    for (int w = threadIdx.x; w < NNODE / 2; w += 256) pk[w] = prow32[w];
    __syncthreads();
    const int2* cp = (const int2*)conn + (size_t)b * NEDGE + c * CHUNKE;
    int* edb = edge_dst + (size_t)b * EDPAD;
    for (int i = threadIdx.x; i < CHUNKE; i += 256){
      int2 e = cp[i];
      int sh1 = (e.x & 1) << 4, sh2 = (e.y & 1) << 4;
      u32 o1 = atomicAdd(&pk[e.x >> 1], 1u << sh1);
      edb[rs[e.x] + (int)((o1 >> sh1) & 0xffffu)] = e.y;
      u32 o2 = atomicAdd(&pk[e.y >> 1], 1u << sh2);
      edb[rs[e.y] + (int)((o2 >> sh2) & 0xffffu)] = e.x;
    }
  } else {
    // ---- pad_fill (+ sentinel gat rows + batch tail fill) ----
    int p = blk - 1506;
    if (p == 0){
      size_t base = (size_t)MROWS * 64;
      gat0[base + threadIdx.x] = 0;
      gat1[base + threadIdx.x] = 0;
    }
    int b = p / 40, j = p % 40;
    const int* rs = row_start + b * (NNODE + 1);
    int sent = 40000 - 9999 * b;   // local d -> global gat row 40000+b (zero)
    int* edb = edge_dst + (size_t)b * EDPAD;
    if (j == 0){                    // fill uninitialized batch tail
      int T = rs[NNODE];
      for (int q = T + (int)threadIdx.x; q < EDPAD; q += 256) edb[q] = sent;
    }
    int n = j * 256 + threadIdx.x;
    if (n < NNODE){
      int s = rs[n] + deg[b * NNODE + n];
      int epad = rs[n + 1];
      for (int q = s; q < epad; q++) edb[q] = sent;
    }
  }
}

// mid: states = tanh(sa + lg@Wl + b); then eah/EL/S for next iter.
__global__ void __launch_bounds__(256) fused_mid(const u32* __restrict__ lgsa,
    const u16* __restrict__ Wt, const float* __restrict__ biasf,
    _Float16* __restrict__ eah, u32* __restrict__ gat0, u32* __restrict__ gat1){
  __shared__ u16 lds[2][16 * 136];
  __shared__ _Float16 eat[2][16 * 128];
  const int lane = threadIdx.x & 63, wave = threadIdx.x >> 6;
  const int t = wave >> 1, ch = wave & 1, cofs = ch * 64;
  const int r0 = blockIdx.x * 32 + t * 16;
  const int lm = lane & 15, lq = lane >> 4;
  f32x4_t acc[4];
  #pragma unroll
  for (int i = 0; i < 4; i++) acc[i] = (f32x4_t){0.f, 0.f, 0.f, 0.f};
  gemm_tile4_packed(lgsa + (size_t)(r0 + lm) * 128, Wt + 49152, lm, lq, cofs, acc);
  #pragma unroll
  for (int nb = 0; nb < 4; nb++){
    int col = cofs + nb * 16 + lm;
    float bb = biasf[col];
    #pragma unroll
    for (int i = 0; i < 4; i++){
      int row = r0 + lq * 4 + i;
      u32 v = lgsa[(size_t)row * 128 + col];
      u16 hb = (u16)(v >> 16);
      float sa = (float)(*(const _Float16*)&hb);
      lds[t][(lq * 4 + i) * 136 + col] = f2bf(fast_tanh(sa + acc[nb][i] + bb));
    }
  }
  __syncthreads();
  phase2_awlaw4(&lds[t][0], Wt, biasf, lm, lq, cofs, r0, &eat[t][0], ch ? gat1 : gat0);
  __syncthreads();
  eah_writeback(&eat[0][0], eah, blockIdx.x * 32, threadIdx.x);
}

// final: out = tanh(sa + lg@Wl + b), fp32 or bf16 per flag.
__global__ void __launch_bounds__(256) final_out(const u32* __restrict__ lgsa,
    const u16* __restrict__ Wt, const float* __restrict__ biasf,
    const int* __restrict__ flag, void* __restrict__ outp){
  const int lane = threadIdx.x & 63, wave = threadIdx.x >> 6;
  const int t = wave >> 1, ch = wave & 1, cofs = ch * 64;
  const int r0 = blockIdx.x * 32 + t * 16;
  const int lm = lane & 15, lq = lane >> 4;
  bool f32out = (*flag != 0);
  f32x4_t acc[4];
  #pragma unroll
  for (int i = 0; i < 4; i++) acc[i] = (f32x4_t){0.f, 0.f, 0.f, 0.f};
  gemm_tile4_packed(lgsa + (size_t)(r0 + lm) * 128, Wt + 49152, lm, lq, cofs, acc);
  #pragma unroll
  for (int nb = 0; nb < 4; nb++){
    int col = cofs + nb * 16 + lm;
    float bb = biasf[col];
    #pragma unroll
    for (int i = 0; i < 4; i++){
      int row = r0 + lq * 4 + i;
      u32 vv = lgsa[(size_t)row * 128 + col];
      u16 hb = (u16)(vv >> 16);
      float sa = (float)(*(const _Float16*)&hb);
      float v = fast_tanh(sa + acc[nb][i] + bb);
      if (f32out) ((float*)outp)[(size_t)row * 128 + col] = v;
      else        ((u16*)  outp)[(size_t)row * 128 + col] = f2bf(v);
    }
  }
}

// ---------------- edge gather: 2 node-chains per wave (R20, verified) ---------
__device__ __forceinline__ void acc_mix(u32 g, float one, float& a1, float& a2){
  asm("v_fma_mix_f32 %0, %2, %3, %0 op_sel:[0,0,0] op_sel_hi:[1,0,0]\n\t"
      "v_fma_mix_f32 %1, %2, %2, %1 op_sel:[0,1,0] op_sel_hi:[1,1,0]"
      : "+v"(a1), "+v"(a2)
      : "v"(g), "v"(one));
}

__device__ __forceinline__ u32 gath1(const u32* __restrict__ gh, int d, int c){
  const u32* p = (const u32*)((const char*)gh + ((size_t)(u32)d << 8));
  return p[c];
}

#define LDIDX(d, p) { const int* ep_ = (p); _Pragma("unroll") \
  for (int j = 0; j < 8; j++) d[j] = __builtin_amdgcn_readfirstlane(ep_[j]); }
#define GATH8(g, d) { _Pragma("unroll") \
  for (int j = 0; j < 8; j++) g[j] = gath1(gh, d[j], c); }
#define CONS8(g, s1, s2, t1, t2) { _Pragma("unroll") \
  for (int j = 0; j < 8; j++) acc_mix(g[j], one, (j & 1) ? t1 : s1, (j & 1) ? t2 : s2); }

__global__ void __launch_bounds__(128, 6) edge_kernel(const _Float16* __restrict__ eah,
    const u32* __restrict__ gat0, const u32* __restrict__ gat1,
    const int* __restrict__ row_start, const int* __restrict__ edge_dst,
    u32* __restrict__ lgsa){
  int blk = blockIdx.x;
  int xcd = blk & 7;
  int b = xcd >> 1, h = xcd & 1;
  int i = blk >> 3;                          // 0..2499
  int w = (int)(threadIdx.x >> 6);
  int nA = i * 4 + w * 2, nB = nA + 1;
  int c = threadIdx.x & 63;
  const u32* gh = (h ? gat1 : gat0) + (size_t)b * NNODE * 64;
  const int* rs = row_start + b * (NNODE + 1);
  int eA  = __builtin_amdgcn_readfirstlane(rs[nA]);
  int eA1 = __builtin_amdgcn_readfirstlane(rs[nA + 1]);
  int eB1 = __builtin_amdgcn_readfirstlane(rs[nB + 1]);
  int eB = eA1;
  const int* ed = edge_dst + (size_t)b * EDPAD;

  float eaA = (float)eah[(size_t)(b * NNODE + nA) * 128 + h * 64 + c];
  float eaB = (float)eah[(size_t)(b * NNODE + nB) * 128 + h * 64 + c];
  u32 selfA = gh[((size_t)nA << 6) + c];
  u32 selfB = gh[((size_t)nB << 6) + c];
  const float one = 1.0f;

  float sA1=0.f, sA2=0.f, tA1=0.f, tA2=0.f;
  float sB1=0.f, sB2=0.f, tB1=0.f, tB2=0.f;
  int ngA = (eA1 - eA) >> 3, ngB = (eB1 - eB) >> 3;  // rows padded: len%8==0
  int dA[8], dB[8]; u32 gA[8], gB[8], hA[8], hB[8];

  if (ngA){ LDIDX(dA, ed + eA); }
  if (ngB){ LDIDX(dB, ed + eB); }
  if (ngA){ GATH8(gA, dA); eA += 8; LDIDX(dA, ed + eA); }
  if (ngB){ GATH8(gB, dB); eB += 8; LDIDX(dB, ed + eB); }

  int m = ngA < ngB ? ngA : ngB;
  int cons = 0;
  for (; cons + 2 <= m; cons += 2){
    GATH8(hA, dA); eA += 8; LDIDX(dA, ed + eA);
    GATH8(hB, dB); eB += 8; LDIDX(dB, ed + eB);
    CONS8(gA, sA1, sA2, tA1, tA2);
    CONS8(gB, sB1, sB2, tB1, tB2);
    GATH8(gA, dA); eA += 8; LDIDX(dA, ed + eA);
    GATH8(gB, dB); eB += 8; LDIDX(dB, ed + eB);
    CONS8(hA, sA1, sA2, tA1, tA2);
    CONS8(hB, sB1, sB2, tB1, tB2);
  }

  { int rem = ngA - cons;
    if (rem > 0){
      int k = 1;
      for (; k + 1 < rem; k += 2){
        GATH8(hA, dA); eA += 8; LDIDX(dA, ed + eA);
        CONS8(gA, sA1, sA2, tA1, tA2);
        GATH8(gA, dA); eA += 8; LDIDX(dA, ed + eA);
        CONS8(hA, sA1, sA2, tA1, tA2);
      }
      if (k < rem){
        GATH8(hA, dA);
        CONS8(gA, sA1, sA2, tA1, tA2);
        CONS8(hA, sA1, sA2, tA1, tA2);
      } else {
        CONS8(gA, sA1, sA2, tA1, tA2);
      }
    }
  }
  { int rem = ngB - cons;
    if (rem > 0){
      int k = 1;
      for (; k + 1 < rem; k += 2){
        GATH8(hB, dB); eB += 8; LDIDX(dB, ed + eB);
        CONS8(gB, sB1, sB2, tB1, tB2);
        GATH8(gB, dB); eB += 8; LDIDX(dB, ed + eB);
        CONS8(hB, sB1, sB2, tB1, tB2);
      }
      if (k < rem){
        GATH8(hB, dB);
        CONS8(gB, sB1, sB2, tB1, tB2);
        CONS8(hB, sB1, sB2, tB1, tB2);
      } else {
        CONS8(gB, sB1, sB2, tB1, tB2);
      }
    }
  }

  sA1 += tA1; sA2 += tA2; sB1 += tB1; sB2 += tB2;
  { float inv = __builtin_amdgcn_rcpf(fmaf(eaA, sA1, 1.0f));
    float lg = eaA * sA2 * inv;
    u16 hb = (u16)(selfA >> 16);
    float s_self = (float)(*(const _Float16*)&hb);
    _Float16 hs = (_Float16)(s_self * inv);
    u32 pk = (u32)f2bf(lg) | ((u32)(*(const u16*)&hs) << 16);
    lgsa[(size_t)(b * NNODE + nA) * 128 + h * 64 + c] = pk; }
  { float inv = __builtin_amdgcn_rcpf(fmaf(eaB, sB1, 1.0f));
    float lg = eaB * sB2 * inv;
    u16 hb = (u16)(selfB >> 16);
    float s_self = (float)(*(const _Float16*)&hb);
    _Float16 hs = (_Float16)(s_self * inv);
    u32 pk = (u32)f2bf(lg) | ((u32)(*(const u16*)&hs) << 16);
    lgsa[(size_t)(b * NNODE + nB) * 128 + h * 64 + c] = pk; }
}

// ---------------- host launcher ----------------------------------------------
extern "C" void kernel_launch(void* const* d_in, const int* in_sizes, int n_in,
                              void* d_out, int out_size, void* d_ws, size_t ws_size,
                              hipStream_t stream){
  (void)in_sizes; (void)n_in; (void)ws_size; (void)out_size;
  const void* objects = d_in[0];
  const void* Wo      = d_in[1];
  const void* Wa      = d_in[2];
  const void* Wla     = d_in[3];
  const void* attn_b  = d_in[4];
  const void* Wl      = d_in[5];
  const void* state_b = d_in[6];
  const int*  conn    = (const int*)d_in[7];

  char* base = (char*)d_ws;
  size_t off = 0;
  auto alloc = [&](size_t bytes) -> char* {
    char* p = base + off;
    off = (off + bytes + 255) & ~(size_t)255;
    return p;
  };
  int*      flag      = (int*)     alloc(256);
  u16*      Wt        = (u16*)     alloc((size_t)4 * 16384 * 2);
  float*    biasf     = (float*)   alloc(256 * 4);
  _Float16* eah       = (_Float16*)alloc((size_t)MROWS * 128 * 2);       // exp(aW) fp16
  u32*      gat0      = (u32*)     alloc((size_t)(MROWS + 4) * 64 * 4);  // ch 0-63 {S|EL} + 4 zero rows
  u32*      gat1      = (u32*)     alloc((size_t)(MROWS + 4) * 64 * 4);  // ch 64-127 + 4 zero rows
  u32*      lgsa      = (u32*)     alloc((size_t)MROWS * 128 * 4);       // {lg bf16 | sa fp16}
  u16*      partial   = (u16*)     alloc((size_t)BATCH * NCHUNK * PADN * 2);
  int*      row_start = (int*)     alloc((size_t)BATCH * (NNODE + 1) * 4);
  int*      edge_dst  = (int*)     alloc((size_t)BATCH * EDPAD * 4);     // padded CSR
  int*      deg       = (int*)     alloc((size_t)MROWS * 4);
  int*      bsum      = (int*)     alloc(160 * 4);

  k1_prep_hist<<<513, 256, 0, stream>>>(conn, partial, objects, Wo, Wa, Wla, Wl,
                                        attn_b, state_b, flag, Wt, biasf);
  csr_colscan<<<160, 256, 0, stream>>>(partial, row_start, bsum, deg);
  scanC<<<160, 256, 0, stream>>>(row_start, bsum);
  k4_init_fill_pad<<<1666, 256, 0, stream>>>(objects, flag, Wt, biasf, eah,
                                             gat0, gat1, conn, partial,
                                             row_start, edge_dst, deg);

  edge_kernel<<<MROWS / 2, 128, 0, stream>>>(eah, gat0, gat1, row_start, edge_dst, lgsa);
  fused_mid<<<MROWS / 32, 256, 0, stream>>>(lgsa, Wt, biasf, eah, gat0, gat1);
  edge_kernel<<<MROWS / 2, 128, 0, stream>>>(eah, gat0, gat1, row_start, edge_dst, lgsa);
  fused_mid<<<MROWS / 32, 256, 0, stream>>>(lgsa, Wt, biasf, eah, gat0, gat1);
  edge_kernel<<<MROWS / 2, 128, 0, stream>>>(eah, gat0, gat1, row_start, edge_dst, lgsa);
  final_out<<<MROWS / 32, 256, 0, stream>>>(lgsa, Wt, biasf, flag, d_out);
}

// Round 15
// 339.871 us; speedup vs baseline: 1.2054x; 1.0101x over previous
//
#include <hip/hip_runtime.h>
#include <hip/hip_bf16.h>

// AttentiveGraph: B=4, N=10000, E=160000, C=F=128, 3 iterations.
// R25 = revert to R21 (session best, 338.96us measured). Rationale:
// R22 (4-pass fill, 352), R23 (global-atomic fill, 410), R24 (packed-cursor
// fill, 343) all regressed vs R21; R24 proved LDS was NOT K4's occupancy
// limiter (20KB vs 40KB -> occupancy unchanged at ~23%), and K4 at 60MB/50us
// is latency-structural, not BW-bound. Edge kernel bracketed at ~40us by 5
// structural variants (3 MLP nulls, 2 footprint regressions). Serial chain
// fully fused where dependencies allow (13 -> 10 dispatches).
// Structure: K1 = csr_hist || prep_weights; colscan; scanC(+scanB);
// K4 = fused_init || csr_fill(LDS u32 cursors) || pad_fill(+sentinel+tail);
// 3x [edge (R20 2-chain scalar ping-pong, fma_mix) ; fused_mid] ; final_out.

#define BATCH 4
#define NNODE 10000
#define NEDGE 160000
#define TWOE  (2*NEDGE)
#define MROWS (BATCH*NNODE)   // 40000
#define NCHUNK 64
#define CHUNKE (NEDGE/NCHUNK) // 2500
#define PADN  10240
#define EDPAD (TWOE + 8*NNODE) // 400000: padded edge capacity per batch

typedef unsigned short u16;
typedef unsigned int   u32;
typedef __attribute__((ext_vector_type(8))) short bf16x8_t;
typedef __attribute__((ext_vector_type(4))) float f32x4_t;

__device__ __forceinline__ float b2f(u16 h){ return __uint_as_float(((u32)h) << 16); }
__device__ __forceinline__ u16 f2bf(float f){
  u32 u = __float_as_uint(f);
  return (u16)((u + 0x7fffu + ((u >> 16) & 1u)) >> 16);   // RNE
}
__device__ __forceinline__ float fast_tanh(float x){
  float e = __expf(2.0f * x);
  return fmaf(-2.0f, __builtin_amdgcn_rcpf(e + 1.0f), 1.0f);
}

__device__ __forceinline__ void chunk_of(int blk, int& b, int& c){
  int xcd = blk & 7;
  b = xcd >> 1;
  c = ((blk >> 3) << 1) | (xcd & 1);           // 0..63
}

// ---------------- K1: csr_hist [0,256) || prep_weights [256,513) --------------
__global__ void __launch_bounds__(256) k1_prep_hist(const int* __restrict__ conn,
    u16* __restrict__ partial,
    const void* __restrict__ objects,
    const void* __restrict__ Wo, const void* __restrict__ Wa,
    const void* __restrict__ Wla, const void* __restrict__ Wl,
    const void* __restrict__ ab, const void* __restrict__ sb,
    int* __restrict__ flag, u16* __restrict__ Wt, float* __restrict__ biasf){
  __shared__ u32 hist[NNODE];
  __shared__ int zc, hc;
  if (blockIdx.x < 256){
    // ---- csr_hist ----
    int b, c; chunk_of(blockIdx.x, b, c);
    for (int n = threadIdx.x; n < NNODE; n += 256) hist[n] = 0;
    __syncthreads();
    const int2* cp = (const int2*)conn + (size_t)b * NEDGE + c * CHUNKE;
    for (int i = threadIdx.x; i < CHUNKE; i += 256){
      int2 e = cp[i];
      atomicAdd(&hist[e.x], 1);
      atomicAdd(&hist[e.y], 1);
    }
    __syncthreads();
    u16* prow = partial + (size_t)(b * NCHUNK + c) * PADN;
    for (int n = threadIdx.x; n < NNODE; n += 256) prow[n] = (u16)hist[n];
  } else {
    // ---- prep_weights (with fused dtype probe) ----
    if (threadIdx.x == 0){ zc = 0; hc = 0; }
    __syncthreads();
    const u32* objw = (const u32*)objects;
    int z = 0, hcnt = 0;
    for (int i = threadIdx.x; i < 1024; i += 256){
      u32 lo = objw[i] & 0xffffu;
      if (lo == 0) z++;
      if (((lo >> 7) & 0xffu) >= 160u) hcnt++;
    }
    atomicAdd(&zc, z); atomicAdd(&hc, hcnt);
    __syncthreads();
    bool f = (hc > 0 || zc > 512);              // 1 = fp32 storage
    int p = blockIdx.x - 256;
    if (p == 0 && threadIdx.x == 0) *flag = f ? 1 : 0;
    int idx = p * 256 + threadIdx.x;
    if (idx < 65536){
      int m = idx >> 14, k = (idx >> 7) & 127, c = idx & 127;
      const void* src = (m == 0) ? Wo : (m == 1) ? Wa : (m == 2) ? Wla : Wl;
      u16 h = f ? f2bf(((const float*)src)[k * 128 + c]) : ((const u16*)src)[k * 128 + c];
      Wt[m * 16384 + c * 128 + k] = h;
    } else {
      int t = idx - 65536;
      const void* src = (t < 128) ? sb : ab;
      int i = t & 127;
      biasf[t] = f ? ((const float*)src)[i] : b2f(((const u16*)src)[i]);
    }
  }
}

// ---------------- CSR scans ---------------------------------------------------
__global__ void __launch_bounds__(256) csr_colscan(u16* __restrict__ partial,
    int* __restrict__ row_start, int* __restrict__ bsum, int* __restrict__ deg){
  int b = blockIdx.x / 40, w = blockIdx.x % 40;
  int n = w * 256 + threadIdx.x;
  u32 run = 0;
  if (n < NNODE){
    #pragma unroll 8
    for (int c = 0; c < NCHUNK; c++){
      size_t idx = (size_t)(b * NCHUNK + c) * PADN + n;
      u32 v = partial[idx];
      partial[idx] = (u16)run;
      run += v;
    }
  }
  u32 pad = (run + 7u) & ~7u;
  __shared__ u32 buf[256];
  buf[threadIdx.x] = pad;
  __syncthreads();
  for (int off = 1; off < 256; off <<= 1){
    u32 x = (threadIdx.x >= (unsigned)off) ? buf[threadIdx.x - off] : 0;
    __syncthreads();
    buf[threadIdx.x] += x;
    __syncthreads();
  }
  u32 incl = buf[threadIdx.x];
  if (n < NNODE){
    row_start[b * (NNODE + 1) + n] = (int)(incl - pad);  // window-local padded
    deg[b * NNODE + n] = (int)run;
  }
  if (threadIdx.x == 255) bsum[blockIdx.x] = (int)incl;
}

// scanC with scanB folded in.
__global__ void scanC(int* __restrict__ row_start, const int* __restrict__ bsum){
  int b = blockIdx.x / 40, j = blockIdx.x % 40;
  int n = j * 256 + threadIdx.x;
  int off = 0;
  for (int q = b * 40; q < b * 40 + j; q++) off += bsum[q];
  if (n < NNODE) row_start[b * (NNODE + 1) + n] += off;
  if (j == 39 && threadIdx.x == 0)
    row_start[b * (NNODE + 1) + NNODE] = off + bsum[b * 40 + 39];
}

// ---------------- MFMA helpers (wave = 16 rows x 64 cols) ---------------------
__device__ __forceinline__ void gemm_tile4(const u16* __restrict__ arow,
    const u16* __restrict__ wt, int lm, int lq, int cofs, f32x4_t acc[4]){
  #pragma unroll
  for (int ks = 0; ks < 4; ks++){
    bf16x8_t a = *(const bf16x8_t*)(arow + ks * 32);
    #pragma unroll
    for (int nb = 0; nb < 4; nb++){
      bf16x8_t bfr = *(const bf16x8_t*)(wt + (cofs + nb * 16 + lm) * 128 + ks * 32 + lq * 8);
      acc[nb] = __builtin_amdgcn_mfma_f32_16x16x32_bf16(a, bfr, acc[nb], 0, 0, 0);
    }
  }
}

__device__ __forceinline__ void gemm_tile4_packed(const u32* __restrict__ Lrow,
    const u16* __restrict__ wt, int lm, int lq, int cofs, f32x4_t acc[4]){
  #pragma unroll
  for (int ks = 0; ks < 4; ks++){
    uint4 wa = *(const uint4*)(Lrow + ks * 32 + lq * 8);
    uint4 wb = *(const uint4*)(Lrow + ks * 32 + lq * 8 + 4);
    bf16x8_t a;
    a[0] = (short)wa.x; a[1] = (short)wa.y; a[2] = (short)wa.z; a[3] = (short)wa.w;
    a[4] = (short)wb.x; a[5] = (short)wb.y; a[6] = (short)wb.z; a[7] = (short)wb.w;
    #pragma unroll
    for (int nb = 0; nb < 4; nb++){
      bf16x8_t bfr = *(const bf16x8_t*)(wt + (cofs + nb * 16 + lm) * 128 + ks * 32 + lq * 8);
      acc[nb] = __builtin_amdgcn_mfma_f32_16x16x32_bf16(a, bfr, acc[nb], 0, 0, 0);
    }
  }
}

// phase 2: states tile (LDS, pointer-based) -> gat {S fp16 hi | EL fp16 lo}
// u32 stores + ea fp16 into eat tile.
__device__ __forceinline__ void phase2_awlaw4(const u16* __restrict__ ldstile,
    const u16* __restrict__ Wt, const float* __restrict__ biasf,
    int lm, int lq, int cofs, int r0, _Float16* __restrict__ eat,
    u32* __restrict__ ghw){
  const u16* Wta  = Wt + 16384;
  const u16* Wtla = Wt + 32768;
  const u16* ldsrow = ldstile + lm * 136 + lq * 8;
  f32x4_t accA[4], accL[4];
  #pragma unroll
  for (int i = 0; i < 4; i++){ accA[i] = (f32x4_t){0.f,0.f,0.f,0.f}; accL[i] = (f32x4_t){0.f,0.f,0.f,0.f}; }
  #pragma unroll
  for (int ks = 0; ks < 4; ks++){
    bf16x8_t a = *(const bf16x8_t*)(ldsrow + ks * 32);
    #pragma unroll
    for (int nb = 0; nb < 4; nb++){
      bf16x8_t ba = *(const bf16x8_t*)(Wta  + (cofs + nb * 16 + lm) * 128 + ks * 32 + lq * 8);
      bf16x8_t bl = *(const bf16x8_t*)(Wtla + (cofs + nb * 16 + lm) * 128 + ks * 32 + lq * 8);
      accA[nb] = __builtin_amdgcn_mfma_f32_16x16x32_bf16(a, ba, accA[nb], 0, 0, 0);
      accL[nb] = __builtin_amdgcn_mfma_f32_16x16x32_bf16(a, bl, accL[nb], 0, 0, 0);
    }
  }
  #pragma unroll
  for (int nb = 0; nb < 4; nb++){
    int col = cofs + nb * 16 + lm;
    float bb = biasf[128 + col];
    #pragma unroll
    for (int i = 0; i < 4; i++){
      int row = r0 + lq * 4 + i;
      float ea = fminf(__expf(accA[nb][i]), 60000.0f);   // fp16-safe
      eat[(lq * 4 + i) * 128 + col] = (_Float16)ea;
      _Float16 elh = (_Float16)fminf(__expf(accL[nb][i] + bb), 60000.0f);
      u16 sbf = ldstile[(lq * 4 + i) * 136 + col];
      _Float16 sh = (_Float16)b2f(sbf);                  // bf16 -> fp16 exact
      u32 elu = (u32)(*(const u16*)&elh);
      u32 shu = (u32)(*(const u16*)&sh);
      ghw[(size_t)row * 64 + (col & 63)] = elu | (shu << 16);
    }
  }
}

// coalesced eah writeback: 2 tiles x 16 rows x 128 fp16 = 8KB, 16B/thread x2.
__device__ __forceinline__ void eah_writeback(const _Float16* __restrict__ eat,
    _Float16* __restrict__ eah, int blk_r0, int tid){
  const uint4* src = (const uint4*)eat;       // 512 x 16B
  uint4* dst = (uint4*)(eah + (size_t)blk_r0 * 128);
  dst[tid]       = src[tid];
  dst[tid + 256] = src[tid + 256];
}

// init body (pointer-based shared), shared by K4.
__device__ __forceinline__ void fused_init_body(int blk, int tid,
    const void* __restrict__ obj_raw, const int* __restrict__ flag,
    const u16* __restrict__ Wt, const float* __restrict__ biasf,
    _Float16* __restrict__ eah, u32* __restrict__ gat0, u32* __restrict__ gat1,
    u16* __restrict__ lds, _Float16* __restrict__ eat){
  const int lane = tid & 63, wave = tid >> 6;
  const int t = wave >> 1, ch = wave & 1, cofs = ch * 64;
  const int r0 = blk * 32 + t * 16;
  const int lm = lane & 15, lq = lane >> 4;
  u16* ldsT = lds + t * 2176;                  // 16*136
  _Float16* eatT = eat + t * 2048;             // 16*128
  f32x4_t acc[4];
  #pragma unroll
  for (int i = 0; i < 4; i++) acc[i] = (f32x4_t){0.f, 0.f, 0.f, 0.f};
  if (*flag){
    const float* arow = (const float*)obj_raw + (size_t)(r0 + lm) * 128 + lq * 8;
    #pragma unroll
    for (int ks = 0; ks < 4; ks++){
      float4 fa = *(const float4*)(arow + ks * 32);
      float4 fb = *(const float4*)(arow + ks * 32 + 4);
      bf16x8_t a;
      a[0] = (short)f2bf(fa.x); a[1] = (short)f2bf(fa.y);
      a[2] = (short)f2bf(fa.z); a[3] = (short)f2bf(fa.w);
      a[4] = (short)f2bf(fb.x); a[5] = (short)f2bf(fb.y);
      a[6] = (short)f2bf(fb.z); a[7] = (short)f2bf(fb.w);
      #pragma unroll
      for (int nb = 0; nb < 4; nb++){
        bf16x8_t bfr = *(const bf16x8_t*)(Wt + (cofs + nb * 16 + lm) * 128 + ks * 32 + lq * 8);
        acc[nb] = __builtin_amdgcn_mfma_f32_16x16x32_bf16(a, bfr, acc[nb], 0, 0, 0);
      }
    }
  } else {
    gemm_tile4((const u16*)obj_raw + (size_t)(r0 + lm) * 128 + lq * 8, Wt, lm, lq, cofs, acc);
  }
  #pragma unroll
  for (int nb = 0; nb < 4; nb++){
    int col = cofs + nb * 16 + lm;
    float bb = biasf[col];
    #pragma unroll
    for (int i = 0; i < 4; i++)
      ldsT[(lq * 4 + i) * 136 + col] = f2bf(fast_tanh(acc[nb][i] + bb));
  }
  __syncthreads();
  phase2_awlaw4(ldsT, Wt, biasf, lm, lq, cofs, r0, eatT, ch ? gat1 : gat0);
  __syncthreads();
  eah_writeback(eat, eah, blk * 32, tid);
}

// ---------------- K4: fused_init || csr_fill || pad_fill ----------------------
__global__ void __launch_bounds__(256) k4_init_fill_pad(
    const void* __restrict__ obj_raw, const int* __restrict__ flag,
    const u16* __restrict__ Wt, const float* __restrict__ biasf,
    _Float16* __restrict__ eah, u32* __restrict__ gat0, u32* __restrict__ gat1,
    const int* __restrict__ conn, const u16* __restrict__ partial,
    const int* __restrict__ row_start, int* __restrict__ edge_dst,
    const int* __restrict__ deg){
  __shared__ __align__(16) char smem[40960];
  int blk = blockIdx.x;
  if (blk < 1250){
    // ---- fused_init ----
    u16* lds = (u16*)smem;                       // 8704B
    _Float16* eat = (_Float16*)(smem + 8704);    // 8192B
    fused_init_body(blk, (int)threadIdx.x, obj_raw, flag, Wt, biasf,
                    eah, gat0, gat1, lds, eat);
  } else if (blk < 1506){
    // ---- csr_fill ----
    int b, c; chunk_of(blk - 1250, b, c);
    u32* cur = (u32*)smem;                       // 40000B
    const u16* prow = partial + (size_t)(b * NCHUNK + c) * PADN;
    const int* rs = row_start + b * (NNODE + 1);
    for (int n = threadIdx.x; n < NNODE; n += 256) cur[n] = (u32)rs[n] + prow[n];
    __syncthreads();
    const int2* cp = (const int2*)conn + (size_t)b * NEDGE + c * CHUNKE;
    int* edb = edge_dst + (size_t)b * EDPAD;
    for (int i = threadIdx.x; i < CHUNKE; i += 256){
      int2 e = cp[i];
      u32 p1 = atomicAdd(&cur[e.x], 1); edb[p1] = e.y;
      u32 p2 = atomicAdd(&cur[e.y], 1); edb[p2] = e.x;
    }
  } else {
    // ---- pad_fill (+ sentinel gat rows + batch tail fill) ----
    int p = blk - 1506;
    if (p == 0){
      size_t base = (size_t)MROWS * 64;
      gat0[base + threadIdx.x] = 0;
      gat1[base + threadIdx.x] = 0;
    }
    int b = p / 40, j = p % 40;
    const int* rs = row_start + b * (NNODE + 1);
    int sent = 40000 - 9999 * b;   // local d -> global gat row 40000+b (zero)
    int* edb = edge_dst + (size_t)b * EDPAD;
    if (j == 0){                    // fill uninitialized batch tail
      int T = rs[NNODE];
      for (int q = T + (int)threadIdx.x; q < EDPAD; q += 256) edb[q] = sent;
    }
    int n = j * 256 + threadIdx.x;
    if (n < NNODE){
      int s = rs[n] + deg[b * NNODE + n];
      int epad = rs[n + 1];
      for (int q = s; q < epad; q++) edb[q] = sent;
    }
  }
}

// mid: states = tanh(sa + lg@Wl + b); then eah/EL/S for next iter.
__global__ void __launch_bounds__(256) fused_mid(const u32* __restrict__ lgsa,
    const u16* __restrict__ Wt, const float* __restrict__ biasf,
    _Float16* __restrict__ eah, u32* __restrict__ gat0, u32* __restrict__ gat1){
  __shared__ u16 lds[2][16 * 136];
  __shared__ _Float16 eat[2][16 * 128];
  const int lane = threadIdx.x & 63, wave = threadIdx.x >> 6;
  const int t = wave >> 1, ch = wave & 1, cofs = ch * 64;
  const int r0 = blockIdx.x * 32 + t * 16;
  const int lm = lane & 15, lq = lane >> 4;
  f32x4_t acc[4];
  #pragma unroll
  for (int i = 0; i < 4; i++) acc[i] = (f32x4_t){0.f, 0.f, 0.f, 0.f};
  gemm_tile4_packed(lgsa + (size_t)(r0 + lm) * 128, Wt + 49152, lm, lq, cofs, acc);
  #pragma unroll
  for (int nb = 0; nb < 4; nb++){
    int col = cofs + nb * 16 + lm;
    float bb = biasf[col];
    #pragma unroll
    for (int i = 0; i < 4; i++){
      int row = r0 + lq * 4 + i;
      u32 v = lgsa[(size_t)row * 128 + col];
      u16 hb = (u16)(v >> 16);
      float sa = (float)(*(const _Float16*)&hb);
      lds[t][(lq * 4 + i) * 136 + col] = f2bf(fast_tanh(sa + acc[nb][i] + bb));
    }
  }
  __syncthreads();
  phase2_awlaw4(&lds[t][0], Wt, biasf, lm, lq, cofs, r0, &eat[t][0], ch ? gat1 : gat0);
  __syncthreads();
  eah_writeback(&eat[0][0], eah, blockIdx.x * 32, threadIdx.x);
}

// final: out = tanh(sa + lg@Wl + b), fp32 or bf16 per flag.
__global__ void __launch_bounds__(256) final_out(const u32* __restrict__ lgsa,
    const u16* __restrict__ Wt, const float* __restrict__ biasf,
    const int* __restrict__ flag, void* __restrict__ outp){
  const int lane = threadIdx.x & 63, wave = threadIdx.x >> 6;
  const int t = wave >> 1, ch = wave & 1, cofs = ch * 64;
  const int r0 = blockIdx.x * 32 + t * 16;
  const int lm = lane & 15, lq = lane >> 4;
  bool f32out = (*flag != 0);
  f32x4_t acc[4];
  #pragma unroll
  for (int i = 0; i < 4; i++) acc[i] = (f32x4_t){0.f, 0.f, 0.f, 0.f};
  gemm_tile4_packed(lgsa + (size_t)(r0 + lm) * 128, Wt + 49152, lm, lq, cofs, acc);
  #pragma unroll
  for (int nb = 0; nb < 4; nb++){
    int col = cofs + nb * 16 + lm;
    float bb = biasf[col];
    #pragma unroll
    for (int i = 0; i < 4; i++){
      int row = r0 + lq * 4 + i;
      u32 vv = lgsa[(size_t)row * 128 + col];
      u16 hb = (u16)(vv >> 16);
      float sa = (float)(*(const _Float16*)&hb);
      float v = fast_tanh(sa + acc[nb][i] + bb);
      if (f32out) ((float*)outp)[(size_t)row * 128 + col] = v;
      else        ((u16*)  outp)[(size_t)row * 128 + col] = f2bf(v);
    }
  }
}

// ---------------- edge gather: 2 node-chains per wave (R20, verified) ---------
__device__ __forceinline__ void acc_mix(u32 g, float one, float& a1, float& a2){
  asm("v_fma_mix_f32 %0, %2, %3, %0 op_sel:[0,0,0] op_sel_hi:[1,0,0]\n\t"
      "v_fma_mix_f32 %1, %2, %2, %1 op_sel:[0,1,0] op_sel_hi:[1,1,0]"
      : "+v"(a1), "+v"(a2)
      : "v"(g), "v"(one));
}

__device__ __forceinline__ u32 gath1(const u32* __restrict__ gh, int d, int c){
  const u32* p = (const u32*)((const char*)gh + ((size_t)(u32)d << 8));
  return p[c];
}

#define LDIDX(d, p) { const int* ep_ = (p); _Pragma("unroll") \
  for (int j = 0; j < 8; j++) d[j] = __builtin_amdgcn_readfirstlane(ep_[j]); }
#define GATH8(g, d) { _Pragma("unroll") \
  for (int j = 0; j < 8; j++) g[j] = gath1(gh, d[j], c); }
#define CONS8(g, s1, s2, t1, t2) { _Pragma("unroll") \
  for (int j = 0; j < 8; j++) acc_mix(g[j], one, (j & 1) ? t1 : s1, (j & 1) ? t2 : s2); }

__global__ void __launch_bounds__(128, 6) edge_kernel(const _Float16* __restrict__ eah,
    const u32* __restrict__ gat0, const u32* __restrict__ gat1,
    const int* __restrict__ row_start, const int* __restrict__ edge_dst,
    u32* __restrict__ lgsa){
  int blk = blockIdx.x;
  int xcd = blk & 7;
  int b = xcd >> 1, h = xcd & 1;
  int i = blk >> 3;                          // 0..2499
  int w = (int)(threadIdx.x >> 6);
  int nA = i * 4 + w * 2, nB = nA + 1;
  int c = threadIdx.x & 63;
  const u32* gh = (h ? gat1 : gat0) + (size_t)b * NNODE * 64;
  const int* rs = row_start + b * (NNODE + 1);
  int eA  = __builtin_amdgcn_readfirstlane(rs[nA]);
  int eA1 = __builtin_amdgcn_readfirstlane(rs[nA + 1]);
  int eB1 = __builtin_amdgcn_readfirstlane(rs[nB + 1]);
  int eB = eA1;
  const int* ed = edge_dst + (size_t)b * EDPAD;

  float eaA = (float)eah[(size_t)(b * NNODE + nA) * 128 + h * 64 + c];
  float eaB = (float)eah[(size_t)(b * NNODE + nB) * 128 + h * 64 + c];
  u32 selfA = gh[((size_t)nA << 6) + c];
  u32 selfB = gh[((size_t)nB << 6) + c];
  const float one = 1.0f;

  float sA1=0.f, sA2=0.f, tA1=0.f, tA2=0.f;
  float sB1=0.f, sB2=0.f, tB1=0.f, tB2=0.f;
  int ngA = (eA1 - eA) >> 3, ngB = (eB1 - eB) >> 3;  // rows padded: len%8==0
  int dA[8], dB[8]; u32 gA[8], gB[8], hA[8], hB[8];

  if (ngA){ LDIDX(dA, ed + eA); }
  if (ngB){ LDIDX(dB, ed + eB); }
  if (ngA){ GATH8(gA, dA); eA += 8; LDIDX(dA, ed + eA); }
  if (ngB){ GATH8(gB, dB); eB += 8; LDIDX(dB, ed + eB); }

  int m = ngA < ngB ? ngA : ngB;
  int cons = 0;
  for (; cons + 2 <= m; cons += 2){
    GATH8(hA, dA); eA += 8; LDIDX(dA, ed + eA);
    GATH8(hB, dB); eB += 8; LDIDX(dB, ed + eB);
    CONS8(gA, sA1, sA2, tA1, tA2);
    CONS8(gB, sB1, sB2, tB1, tB2);
    GATH8(gA, dA); eA += 8; LDIDX(dA, ed + eA);
    GATH8(gB, dB); eB += 8; LDIDX(dB, ed + eB);
    CONS8(hA, sA1, sA2, tA1, tA2);
    CONS8(hB, sB1, sB2, tB1, tB2);
  }

  { int rem = ngA - cons;
    if (rem > 0){
      int k = 1;
      for (; k + 1 < rem; k += 2){
        GATH8(hA, dA); eA += 8; LDIDX(dA, ed + eA);
        CONS8(gA, sA1, sA2, tA1, tA2);
        GATH8(gA, dA); eA += 8; LDIDX(dA, ed + eA);
        CONS8(hA, sA1, sA2, tA1, tA2);
      }
      if (k < rem){
        GATH8(hA, dA);
        CONS8(gA, sA1, sA2, tA1, tA2);
        CONS8(hA, sA1, sA2, tA1, tA2);
      } else {
        CONS8(gA, sA1, sA2, tA1, tA2);
      }
    }
  }
  { int rem = ngB - cons;
    if (rem > 0){
      int k = 1;
      for (; k + 1 < rem; k += 2){
        GATH8(hB, dB); eB += 8; LDIDX(dB, ed + eB);
        CONS8(gB, sB1, sB2, tB1, tB2);
        GATH8(gB, dB); eB += 8; LDIDX(dB, ed + eB);
        CONS8(hB, sB1, sB2, tB1, tB2);
      }
      if (k < rem){
        GATH8(hB, dB);
        CONS8(gB, sB1, sB2, tB1, tB2);
        CONS8(hB, sB1, sB2, tB1, tB2);
      } else {
        CONS8(gB, sB1, sB2, tB1, tB2);
      }
    }
  }

  sA1 += tA1; sA2 += tA2; sB1 += tB1; sB2 += tB2;
  { float inv = __builtin_amdgcn_rcpf(fmaf(eaA, sA1, 1.0f));
    float lg = eaA * sA2 * inv;
    u16 hb = (u16)(selfA >> 16);
    float s_self = (float)(*(const _Float16*)&hb);
    _Float16 hs = (_Float16)(s_self * inv);
    u32 pk = (u32)f2bf(lg) | ((u32)(*(const u16*)&hs) << 16);
    lgsa[(size_t)(b * NNODE + nA) * 128 + h * 64 + c] = pk; }
  { float inv = __builtin_amdgcn_rcpf(fmaf(eaB, sB1, 1.0f));
    float lg = eaB * sB2 * inv;
    u16 hb = (u16)(selfB >> 16);
    float s_self = (float)(*(const _Float16*)&hb);
    _Float16 hs = (_Float16)(s_self * inv);
    u32 pk = (u32)f2bf(lg) | ((u32)(*(const u16*)&hs) << 16);
    lgsa[(size_t)(b * NNODE + nB) * 128 + h * 64 + c] = pk; }
}

// ---------------- host launcher ----------------------------------------------
extern "C" void kernel_launch(void* const* d_in, const int* in_sizes, int n_in,
                              void* d_out, int out_size, void* d_ws, size_t ws_size,
                              hipStream_t stream){
  (void)in_sizes; (void)n_in; (void)ws_size; (void)out_size;
  const void* objects = d_in[0];
  const void* Wo      = d_in[1];
  const void* Wa      = d_in[2];
  const void* Wla     = d_in[3];
  const void* attn_b  = d_in[4];
  const void* Wl      = d_in[5];
  const void* state_b = d_in[6];
  const int*  conn    = (const int*)d_in[7];

  char* base = (char*)d_ws;
  size_t off = 0;
  auto alloc = [&](size_t bytes) -> char* {
    char* p = base + off;
    off = (off + bytes + 255) & ~(size_t)255;
    return p;
  };
  int*      flag      = (int*)     alloc(256);
  u16*      Wt        = (u16*)     alloc((size_t)4 * 16384 * 2);
  float*    biasf     = (float*)   alloc(256 * 4);
  _Float16* eah       = (_Float16*)alloc((size_t)MROWS * 128 * 2);       // exp(aW) fp16
  u32*      gat0      = (u32*)     alloc((size_t)(MROWS + 4) * 64 * 4);  // ch 0-63 {S|EL} + 4 zero rows
  u32*      gat1      = (u32*)     alloc((size_t)(MROWS + 4) * 64 * 4);  // ch 64-127 + 4 zero rows
  u32*      lgsa      = (u32*)     alloc((size_t)MROWS * 128 * 4);       // {lg bf16 | sa fp16}
  u16*      partial   = (u16*)     alloc((size_t)BATCH * NCHUNK * PADN * 2);
  int*      row_start = (int*)     alloc((size_t)BATCH * (NNODE + 1) * 4);
  int*      edge_dst  = (int*)     alloc((size_t)BATCH * EDPAD * 4);     // padded CSR
  int*      deg       = (int*)     alloc((size_t)MROWS * 4);
  int*      bsum      = (int*)     alloc(160 * 4);

  k1_prep_hist<<<513, 256, 0, stream>>>(conn, partial, objects, Wo, Wa, Wla, Wl,
                                        attn_b, state_b, flag, Wt, biasf);
  csr_colscan<<<160, 256, 0, stream>>>(partial, row_start, bsum, deg);
  scanC<<<160, 256, 0, stream>>>(row_start, bsum);
  k4_init_fill_pad<<<1666, 256, 0, stream>>>(objects, flag, Wt, biasf, eah,
                                             gat0, gat1, conn, partial,
                                             row_start, edge_dst, deg);

  edge_kernel<<<MROWS / 2, 128, 0, stream>>>(eah, gat0, gat1, row_start, edge_dst, lgsa);
  fused_mid<<<MROWS / 32, 256, 0, stream>>>(lgsa, Wt, biasf, eah, gat0, gat1);
  edge_kernel<<<MROWS / 2, 128, 0, stream>>>(eah, gat0, gat1, row_start, edge_dst, lgsa);
  fused_mid<<<MROWS / 32, 256, 0, stream>>>(lgsa, Wt, biasf, eah, gat0, gat1);
  edge_kernel<<<MROWS / 2, 128, 0, stream>>>(eah, gat0, gat1, row_start, edge_dst, lgsa);
  final_out<<<MROWS / 32, 256, 0, stream>>>(lgsa, Wt, biasf, flag, d_out);
}